// Round 3
// baseline (531.433 us; speedup 1.0000x reference)
//
#include <hip/hip_runtime.h>
#include <math.h>

// Problem dims
#define Mm 8
#define Bb 64
#define Ss 1024
#define Kk 256
#define Hh 8
#define HD 32
#define Ff 1024

typedef _Float16 f16x8 __attribute__((ext_vector_type(8)));
typedef float f32x4 __attribute__((ext_vector_type(4)));

// Workspace layout (float offsets). Overlapping regions have disjoint lifetimes.
#define WS_Q      0u
#define WS_U      131072u
#define WS_QDB    1179648u
#define WS_SC     1183744u
#define WS_WPART  5378048u
#define WS_FC     0u         // overlays Q (dead after K2)
#define WS_H1     5378048u   // overlays WPART (dead after K5)
#define WS_GATES  262144u    // overlays U (dead after K3)
#define WS_HPART  1183744u   // overlays SC (dead after K4a); 4x524288 floats

// ---------------------------------------------------------------------------
// K1: q = q0 @ Wq + bq        (M,B,K)
__global__ __launch_bounds__(256) void k1_qproj(
    const float* __restrict__ q0, const float* __restrict__ wq,
    const float* __restrict__ bq, float* __restrict__ qout) {
  __shared__ float q0s[8 * 260];
  const int m = blockIdx.x, b0 = blockIdx.y * 8, t = threadIdx.x;
#pragma unroll
  for (int j = 0; j < 8; ++j)
    q0s[j * 260 + t] = q0[(m * Bb + b0 + j) * Kk + t];
  __syncthreads();
  float acc[8];
  const float bias = bq[m * Kk + t];
#pragma unroll
  for (int j = 0; j < 8; ++j) acc[j] = bias;
  const float* wcol = wq + m * Kk * Kk + t;
  for (int k4 = 0; k4 < Kk / 4; ++k4) {
    const float w0 = wcol[(k4 * 4 + 0) * Kk];
    const float w1 = wcol[(k4 * 4 + 1) * Kk];
    const float w2 = wcol[(k4 * 4 + 2) * Kk];
    const float w3 = wcol[(k4 * 4 + 3) * Kk];
#pragma unroll
    for (int j = 0; j < 8; ++j) {
      const float4 qv = *(const float4*)&q0s[j * 260 + k4 * 4];
      acc[j] += qv.x * w0 + qv.y * w1 + qv.z * w2 + qv.w * w3;
    }
  }
#pragma unroll
  for (int j = 0; j < 8; ++j)
    qout[(m * Bb + b0 + j) * Kk + t] = acc[j];
}

// ---------------------------------------------------------------------------
// K2: u(m,b,h,k) = sum_d Wk[m,k,h*32+d] * q[m,b,h*32+d]
__global__ __launch_bounds__(256) void k2_uproj(
    const float* __restrict__ wk, const float* __restrict__ bk,
    const float* __restrict__ q, float* __restrict__ u,
    float* __restrict__ qdb) {
  __shared__ float qs[64 * 36];
  const int m = blockIdx.x, h = blockIdx.y, t = threadIdx.x;
#pragma unroll
  for (int p = 0; p < 8; ++p) {
    const int idx = p * 256 + t;
    const int d = idx & 31, b = idx >> 5;
    qs[b * 36 + d] = q[(m * Bb + b) * Kk + h * HD + d];
  }
  __syncthreads();
  float acc[64];
#pragma unroll
  for (int b = 0; b < 64; ++b) acc[b] = 0.f;
  const float* wrow = wk + (m * Kk + t) * Kk + h * HD;
#pragma unroll
  for (int d4 = 0; d4 < 8; ++d4) {
    const float4 w4 = *(const float4*)&wrow[d4 * 4];
#pragma unroll
    for (int b = 0; b < 64; ++b) {
      const float4 q4 = *(const float4*)&qs[b * 36 + d4 * 4];
      acc[b] += q4.x * w4.x + q4.y * w4.y + q4.z * w4.z + q4.w * w4.w;
    }
  }
  for (int b = 0; b < 64; ++b)
    u[((m * Bb + b) * Hh + h) * Kk + t] = acc[b];
  if (t < 64) {
    float s = 0.f;
#pragma unroll
    for (int d = 0; d < 32; ++d)
      s += qs[t * 36 + d] * bk[m * Kk + h * HD + d];
    qdb[(m * Bb + t) * Hh + h] = s;
  }
}

// ---------------------------------------------------------------------------
// K3 (fp16 MFMA): raw scores(m,b,h,s) = (key(s,b,:)·u(m,b,h,:) + qdb)/sqrt(32)
// grid (64, 8) : (b, s-tile of 128), 256 threads = 4 waves.
// Wave w owns mh rows 16w..16w+15; 8 s-frags of 16; K=256 in 8 steps of 32.
// A = u (k-contiguous), B = key (k-contiguous) -> natural b128 frag loads.
__global__ __launch_bounds__(256) void k3_scores(
    const float* __restrict__ key, const float* __restrict__ u,
    const float* __restrict__ qdb, float* __restrict__ sc) {
  __shared__ float Us[64 * 36];
  __shared__ float Ks[128 * 36];
  __shared__ float qd[64];
  const int b = blockIdx.x, st0 = blockIdx.y * 128, t = threadIdx.x;
  const int w = t >> 6, lane = t & 63, quad = lane >> 4, l15 = lane & 15;
  if (t < 64) qd[t] = qdb[((t >> 3) * Bb + b) * Hh + (t & 7)];
  f32x4 acc[8];
#pragma unroll
  for (int i = 0; i < 8; ++i) acc[i] = (f32x4){0.f, 0.f, 0.f, 0.f};
  for (int kt = 0; kt < 8; ++kt) {
    __syncthreads();
    // stage U: 64 mh x 32 k (fp32), b128
#pragma unroll
    for (int p = 0; p < 2; ++p) {
      const int idx = p * 256 + t;  // 512 float4
      const int mh = idx >> 3, k4 = idx & 7;
      const float4 v = *(const float4*)&u[(((mh >> 3) * Bb + b) * Hh +
                                           (mh & 7)) * Kk + kt * 32 + k4 * 4];
      *(float4*)&Us[mh * 36 + k4 * 4] = v;
    }
    // stage key: 128 s x 32 k (fp32), b128
#pragma unroll
    for (int p = 0; p < 4; ++p) {
      const int idx = p * 256 + t;  // 1024 float4
      const int s = idx >> 3, k4 = idx & 7;
      const float4 v = *(const float4*)&key[(size_t)(st0 + s) * (Bb * Kk) +
                                            b * Kk + kt * 32 + k4 * 4];
      *(float4*)&Ks[s * 36 + k4 * 4] = v;
    }
    __syncthreads();
    f16x8 af;
    {
      const float4 a0 = *(const float4*)&Us[(w * 16 + l15) * 36 + quad * 8];
      const float4 a1 =
          *(const float4*)&Us[(w * 16 + l15) * 36 + quad * 8 + 4];
      af[0] = (_Float16)a0.x; af[1] = (_Float16)a0.y;
      af[2] = (_Float16)a0.z; af[3] = (_Float16)a0.w;
      af[4] = (_Float16)a1.x; af[5] = (_Float16)a1.y;
      af[6] = (_Float16)a1.z; af[7] = (_Float16)a1.w;
    }
#pragma unroll
    for (int sf = 0; sf < 8; ++sf) {
      const float4 b0 = *(const float4*)&Ks[(sf * 16 + l15) * 36 + quad * 8];
      const float4 b1 =
          *(const float4*)&Ks[(sf * 16 + l15) * 36 + quad * 8 + 4];
      f16x8 bf;
      bf[0] = (_Float16)b0.x; bf[1] = (_Float16)b0.y;
      bf[2] = (_Float16)b0.z; bf[3] = (_Float16)b0.w;
      bf[4] = (_Float16)b1.x; bf[5] = (_Float16)b1.y;
      bf[6] = (_Float16)b1.z; bf[7] = (_Float16)b1.w;
      acc[sf] = __builtin_amdgcn_mfma_f32_16x16x32_f16(af, bf, acc[sf], 0, 0, 0);
    }
  }
  const float scale = 0.17677669529663687f;  // 1/sqrt(32)
#pragma unroll
  for (int sf = 0; sf < 8; ++sf) {
    const int s = st0 + sf * 16 + l15;
#pragma unroll
    for (int r = 0; r < 4; ++r) {
      const int mh = w * 16 + quad * 4 + r;
      sc[(size_t)(((mh >> 3) * Bb + b) * Hh + (mh & 7)) * Ss + s] =
          (acc[sf][r] + qd[mh]) * scale;
    }
  }
}

// ---------------------------------------------------------------------------
// K3b: in-place softmax over s (per m,b,h) + attn_weights = mean over h
__global__ __launch_bounds__(256) void k3b_softmax(float* __restrict__ sc,
                                                   float* __restrict__ out) {
  __shared__ float rows[8 * 1024];
  __shared__ float red[8];
  const int m = blockIdx.x, b = blockIdx.y, t = threadIdx.x;
  const int base = (m * Bb + b) * (Hh * Ss);
  for (int p = 0; p < 32; ++p)
    rows[p * 256 + t] = sc[base + p * 256 + t];
  __syncthreads();
  const int lane = t & 63, wid = t >> 6;
  for (int h = 0; h < 8; ++h) {
    float v0 = rows[h * 1024 + t], v1 = rows[h * 1024 + 256 + t],
          v2 = rows[h * 1024 + 512 + t], v3 = rows[h * 1024 + 768 + t];
    float mx = fmaxf(fmaxf(v0, v1), fmaxf(v2, v3));
    for (int off = 32; off > 0; off >>= 1)
      mx = fmaxf(mx, __shfl_down(mx, off, 64));
    if (lane == 0) red[wid] = mx;
    __syncthreads();
    mx = fmaxf(fmaxf(red[0], red[1]), fmaxf(red[2], red[3]));
    v0 = __expf(v0 - mx); v1 = __expf(v1 - mx);
    v2 = __expf(v2 - mx); v3 = __expf(v3 - mx);
    float sm = v0 + v1 + v2 + v3;
    for (int off = 32; off > 0; off >>= 1) sm += __shfl_down(sm, off, 64);
    if (lane == 0) red[4 + wid] = sm;
    __syncthreads();
    const float inv = 1.f / (red[4] + red[5] + red[6] + red[7]);
    v0 *= inv; v1 *= inv; v2 *= inv; v3 *= inv;
    rows[h * 1024 + t] = v0; rows[h * 1024 + 256 + t] = v1;
    rows[h * 1024 + 512 + t] = v2; rows[h * 1024 + 768 + t] = v3;
    sc[base + h * 1024 + t] = v0; sc[base + h * 1024 + 256 + t] = v1;
    sc[base + h * 1024 + 512 + t] = v2; sc[base + h * 1024 + 768 + t] = v3;
    __syncthreads();
  }
#pragma unroll
  for (int i = 0; i < 4; ++i) {
    const int s = i * 256 + t;
    float sum = 0.f;
#pragma unroll
    for (int h = 0; h < 8; ++h) sum += rows[h * 1024 + s];
    out[131072u + (m * Bb + b) * Ss + s] = sum * 0.125f;
  }
}

// ---------------------------------------------------------------------------
// K4a: partial w(m,b,h,k) = sum_{s in chunk} aw(m,b,h,s)*value(s,b,k)
__global__ __launch_bounds__(256) void k4a_av(const float* __restrict__ value,
                                              const float* __restrict__ aw,
                                              float* __restrict__ wpart) {
  __shared__ float aws[32 * 36];
  __shared__ float vs[32 * 260];
  const int b = blockIdx.x, sc4 = blockIdx.y, mhh = blockIdx.z,
            t = threadIdx.x;
  const int tmh = t & 7, tk = t >> 3;
  float acc[4][8];
#pragma unroll
  for (int a = 0; a < 4; ++a)
#pragma unroll
    for (int j = 0; j < 8; ++j) acc[a][j] = 0.f;
  for (int st = 0; st < 8; ++st) {
    __syncthreads();
    const int s0 = sc4 * 256 + st * 32;
#pragma unroll
    for (int p = 0; p < 4; ++p) {
      const int idx = p * 256 + t;
      const int s = idx & 31, j = idx >> 5;
      const int mh = mhh * 32 + j;
      aws[j * 36 + s] =
          aw[(((mh >> 3) * Bb + b) * Hh + (mh & 7)) * Ss + s0 + s];
    }
#pragma unroll
    for (int p = 0; p < 32; ++p)
      vs[p * 260 + t] = value[(s0 + p) * (Bb * Kk) + b * Kk + t];
    __syncthreads();
#pragma unroll 2
    for (int s4 = 0; s4 < 8; ++s4) {
      float4 av[4];
#pragma unroll
      for (int a = 0; a < 4; ++a)
        av[a] = *(const float4*)&aws[(tmh + 8 * a) * 36 + s4 * 4];
#pragma unroll
      for (int ss = 0; ss < 4; ++ss) {
        const float4 v0 = *(const float4*)&vs[(s4 * 4 + ss) * 260 + tk * 4];
        const float4 v1 =
            *(const float4*)&vs[(s4 * 4 + ss) * 260 + 128 + tk * 4];
#pragma unroll
        for (int a = 0; a < 4; ++a) {
          const float aval = (ss == 0) ? av[a].x
                             : (ss == 1) ? av[a].y
                             : (ss == 2) ? av[a].z : av[a].w;
          acc[a][0] += aval * v0.x; acc[a][1] += aval * v0.y;
          acc[a][2] += aval * v0.z; acc[a][3] += aval * v0.w;
          acc[a][4] += aval * v1.x; acc[a][5] += aval * v1.y;
          acc[a][6] += aval * v1.z; acc[a][7] += aval * v1.w;
        }
      }
    }
  }
  float* wp = wpart + sc4 * 1048576u;
#pragma unroll
  for (int a = 0; a < 4; ++a) {
    const int mh = mhh * 32 + tmh + 8 * a;
    const int rb = (((mh >> 3) * Bb + b) * Hh + (mh & 7)) * Kk;
    float4 r0 = {acc[a][0], acc[a][1], acc[a][2], acc[a][3]};
    float4 r1 = {acc[a][4], acc[a][5], acc[a][6], acc[a][7]};
    *(float4*)&wp[rb + tk * 4] = r0;
    *(float4*)&wp[rb + 128 + tk * 4] = r1;
  }
}

// ---------------------------------------------------------------------------
// K5: w = sum of 4 partials; ctx = w @ Wv_h + bv ; attn_out = ctx @ Wo + bo ;
//     fc_in = relu(concat). grid (8, 64) : (m, b), 256 threads
__global__ __launch_bounds__(256) void k5_ctx(
    const float* __restrict__ wv, const float* __restrict__ bv,
    const float* __restrict__ wo, const float* __restrict__ bo,
    const float* __restrict__ s0in, const float* __restrict__ wpart,
    float* __restrict__ attn_out, float* __restrict__ fc) {
  __shared__ float wsh[2048];
  __shared__ float ctxs[256];
  const int m = blockIdx.x, b = blockIdx.y, t = threadIdx.x;
  const int base = (m * Bb + b) * (Hh * Kk);
#pragma unroll
  for (int p = 0; p < 8; ++p) {
    const int o = base + p * 256 + t;
    wsh[p * 256 + t] = wpart[o] + wpart[1048576u + o] + wpart[2097152u + o] +
                       wpart[3145728u + o];
  }
  __syncthreads();
  const int h = t >> 5;
  float acc = bv[m * Kk + t];
  const float* wvc = wv + m * Kk * Kk + t;
  for (int k4 = 0; k4 < 64; ++k4) {
    const float4 a4 = *(const float4*)&wsh[h * 256 + k4 * 4];
    acc += a4.x * wvc[(k4 * 4 + 0) * Kk] + a4.y * wvc[(k4 * 4 + 1) * Kk] +
           a4.z * wvc[(k4 * 4 + 2) * Kk] + a4.w * wvc[(k4 * 4 + 3) * Kk];
  }
  ctxs[t] = acc;
  __syncthreads();
  float acc2 = bo[m * Kk + t];
  const float* woc = wo + m * Kk * Kk + t;
  for (int k4 = 0; k4 < 64; ++k4) {
    const float4 c4 = *(const float4*)&ctxs[k4 * 4];
    acc2 += c4.x * woc[(k4 * 4 + 0) * Kk] + c4.y * woc[(k4 * 4 + 1) * Kk] +
            c4.z * woc[(k4 * 4 + 2) * Kk] + c4.w * woc[(k4 * 4 + 3) * Kk];
  }
  const int ob = (m * Bb + b) * Kk + t;
  attn_out[ob] = acc2;
  fc[(m * Bb + b) * 512 + t] = fmaxf(acc2, 0.f);
  fc[(m * Bb + b) * 512 + 256 + t] = fmaxf(s0in[ob], 0.f);
}

// ---------------------------------------------------------------------------
// K6 (fp16 MFMA): h1[head] = relu(fc_in @ W1[head] + b1[head])
// grid (8, 8, 8) : (f-tile of 128, m, head), 256 threads = 4 waves.
// Wave w owns b-rows 16w..16w+15; 8 f-frags of 16; K=512 in 16 steps of 32.
// A (fc) staged fp32 [b][k] (k-contig); B (W1) staged TRANSPOSED packed-fp16
// [f][kpair] so B-frags are single b128 reads.
__global__ __launch_bounds__(256) void k6_mlp1(
    const float* __restrict__ fc, const float* __restrict__ w1q,
    const float* __restrict__ w1k, const float* __restrict__ w1v,
    const float* __restrict__ w1s, const float* __restrict__ w1g,
    const float* __restrict__ b1q, const float* __restrict__ b1k,
    const float* __restrict__ b1v, const float* __restrict__ b1s,
    const float* __restrict__ b1g, float* __restrict__ h1) {
  __shared__ float As[64 * 36];      // fc tile fp32
  __shared__ unsigned Wp[128 * 20];  // W1 tile as packed f16 pairs [f][kp]
  const int ft = blockIdx.x, m = blockIdx.y, head = blockIdx.z,
            t = threadIdx.x;
  const float* w1;
  const float* b1;
  if (head == 0)      { w1 = w1q; b1 = b1q; }
  else if (head == 1) { w1 = w1k; b1 = b1k; }
  else if (head == 2) { w1 = w1v; b1 = b1v; }
  else if (head == 3) { w1 = w1s; b1 = b1s; }
  else {
    w1 = w1g + (size_t)(head - 4) * (Mm * 512 * Ff);
    b1 = b1g + (head - 4) * (Mm * Ff);
  }
  w1 += (size_t)m * 512 * Ff;
  b1 += m * Ff;
  const int w = t >> 6, lane = t & 63, quad = lane >> 4, l15 = lane & 15;
  f32x4 acc[8];
#pragma unroll
  for (int i = 0; i < 8; ++i) acc[i] = (f32x4){0.f, 0.f, 0.f, 0.f};
  for (int it = 0; it < 16; ++it) {
    __syncthreads();
    // stage fc: 64 b x 32 k fp32, b128
#pragma unroll
    for (int p = 0; p < 2; ++p) {
      const int idx = p * 256 + t;  // 512 float4
      const int bb = idx >> 3, k4 = idx & 7;
      const float4 v =
          *(const float4*)&fc[(m * Bb + bb) * 512 + it * 32 + k4 * 4];
      *(float4*)&As[bb * 36 + k4 * 4] = v;
    }
    // stage W1 transposed+packed: u32(f,kp) = {f16(W[2kp][f]), f16(W[2kp+1][f])}
#pragma unroll
    for (int p = 0; p < 8; ++p) {
      const int idx = p * 256 + t;  // 2048 u32
      const int f = idx & 127, kp = idx >> 7;
      const float w0 = w1[(size_t)(it * 32 + 2 * kp) * Ff + ft * 128 + f];
      const float w1v = w1[(size_t)(it * 32 + 2 * kp + 1) * Ff + ft * 128 + f];
      union { unsigned u; _Float16 h[2]; } pk;
      pk.h[0] = (_Float16)w0;
      pk.h[1] = (_Float16)w1v;
      Wp[f * 20 + kp] = pk.u;
    }
    __syncthreads();
    f16x8 af;
    {
      const float4 a0 = *(const float4*)&As[(w * 16 + l15) * 36 + quad * 8];
      const float4 a1 =
          *(const float4*)&As[(w * 16 + l15) * 36 + quad * 8 + 4];
      af[0] = (_Float16)a0.x; af[1] = (_Float16)a0.y;
      af[2] = (_Float16)a0.z; af[3] = (_Float16)a0.w;
      af[4] = (_Float16)a1.x; af[5] = (_Float16)a1.y;
      af[6] = (_Float16)a1.z; af[7] = (_Float16)a1.w;
    }
#pragma unroll
    for (int nf = 0; nf < 8; ++nf) {
      const f16x8 bf = *(const f16x8*)&Wp[(nf * 16 + l15) * 20 + quad * 4];
      acc[nf] = __builtin_amdgcn_mfma_f32_16x16x32_f16(af, bf, acc[nf], 0, 0, 0);
    }
  }
  // epilogue: row b = 16w + quad*4 + r, col f = ft*128 + nf*16 + l15
  float* hb = h1 + (size_t)((head * Mm + m) * Bb) * Ff;
#pragma unroll
  for (int nf = 0; nf < 8; ++nf) {
    const int f = ft * 128 + nf * 16 + l15;
    const float bias = b1[f];
#pragma unroll
    for (int r = 0; r < 4; ++r) {
      const int bb = w * 16 + quad * 4 + r;
      hb[(size_t)bb * Ff + f] = fmaxf(acc[nf][r] + bias, 0.f);
    }
  }
}

// ---------------------------------------------------------------------------
// K6b: gates(g,m,b) = sigmoid(h1[4+g,m,b,:] . g_w2[g,m,:] + g_b2[g,m])
__global__ __launch_bounds__(64) void k6b_gates(
    const float* __restrict__ h1, const float* __restrict__ gw2,
    const float* __restrict__ gb2, float* __restrict__ gates) {
  const int gm = blockIdx.x, b = blockIdx.y, t = threadIdx.x;
  const int g = gm >> 3, m = gm & 7;
  const float* hrow = h1 + (size_t)(((4 + g) * Mm + m) * Bb + b) * Ff;
  const float* wrow = gw2 + (g * Mm + m) * Ff;
  float s = 0.f;
#pragma unroll
  for (int i = 0; i < 16; ++i) s += hrow[t + i * 64] * wrow[t + i * 64];
  for (int off = 32; off > 0; off >>= 1) s += __shfl_down(s, off, 64);
  if (t == 0)
    gates[(g * Mm + m) * Bb + b] =
        1.f / (1.f + __expf(-(s + gb2[g * Mm + m])));
}

// ---------------------------------------------------------------------------
// K7a: partial second-layer head outputs over an f-quarter (K=256)
__global__ __launch_bounds__(256) void k7a_mlp2(
    const float* __restrict__ h1, const float* __restrict__ w2q,
    const float* __restrict__ w2k, const float* __restrict__ w2v,
    const float* __restrict__ w2s, float* __restrict__ hpart) {
  __shared__ float Ht[32 * 68];
  __shared__ float Wt[32 * 68];
  const int fq = blockIdx.x >> 2, oc = blockIdx.x & 3;
  const int m = blockIdx.y, head = blockIdx.z, t = threadIdx.x;
  const float* w2 =
      (head == 0) ? w2q : (head == 1) ? w2k : (head == 2) ? w2v : w2s;
  w2 += (size_t)m * Ff * Kk;
  const float* hbase = h1 + (size_t)((head * Mm + m) * Bb) * Ff + fq * 256;
  const int to = t & 15, tb = t >> 4;
  float acc[4][4];
#pragma unroll
  for (int j = 0; j < 4; ++j)
#pragma unroll
    for (int i = 0; i < 4; ++i) acc[j][i] = 0.f;
  for (int it = 0; it < 8; ++it) {
    __syncthreads();
#pragma unroll
    for (int p = 0; p < 8; ++p) {
      const int idx = p * 256 + t;
      const int f = idx & 31, bb = idx >> 5;
      Ht[f * 68 + bb] = hbase[bb * Ff + it * 32 + f];
    }
#pragma unroll
    for (int p = 0; p < 8; ++p) {
      const int idx = p * 256 + t;
      const int o = idx & 63, f = idx >> 6;
      Wt[f * 68 + o] = w2[(fq * 256 + it * 32 + f) * Kk + oc * 64 + o];
    }
    __syncthreads();
#pragma unroll 8
    for (int kk = 0; kk < 32; ++kk) {
      const float4 a4 = *(const float4*)&Ht[kk * 68 + tb * 4];
      const float4 w4 = *(const float4*)&Wt[kk * 68 + to * 4];
      acc[0][0] += a4.x * w4.x; acc[0][1] += a4.x * w4.y;
      acc[0][2] += a4.x * w4.z; acc[0][3] += a4.x * w4.w;
      acc[1][0] += a4.y * w4.x; acc[1][1] += a4.y * w4.y;
      acc[1][2] += a4.y * w4.z; acc[1][3] += a4.y * w4.w;
      acc[2][0] += a4.z * w4.x; acc[2][1] += a4.z * w4.y;
      acc[2][2] += a4.z * w4.z; acc[2][3] += a4.z * w4.w;
      acc[3][0] += a4.w * w4.x; acc[3][1] += a4.w * w4.y;
      acc[3][2] += a4.w * w4.z; acc[3][3] += a4.w * w4.w;
    }
  }
  float* hp =
      hpart + fq * 524288u + (size_t)((head * Mm + m) * Bb) * Kk + oc * 64;
#pragma unroll
  for (int j = 0; j < 4; ++j) {
    const int bb = tb * 4 + j;
    float4 r = {acc[j][0], acc[j][1], acc[j][2], acc[j][3]};
    *(float4*)&hp[bb * Kk + to * 4] = r;
  }
}

// ---------------------------------------------------------------------------
// K7b: out = gate*tanh(relu(p0+p1+p2+p3+b2)) + (1-gate)*x0
__global__ __launch_bounds__(256) void k7b_final(
    const float* __restrict__ hpart, const float* __restrict__ gates,
    const float* __restrict__ b2q, const float* __restrict__ b2k,
    const float* __restrict__ b2v, const float* __restrict__ b2s,
    const float* __restrict__ q0, const float* __restrict__ k0,
    const float* __restrict__ v0, const float* __restrict__ s0,
    float* __restrict__ out) {
  const int idx = blockIdx.x * 256 + threadIdx.x;
  const int o = idx & 255;
  const int b = (idx >> 8) & 63;
  const int m = (idx >> 14) & 7;
  const int head = idx >> 17;
  const float* b2 = (head == 0) ? b2q : (head == 1) ? b2k
                    : (head == 2) ? b2v : b2s;
  const float* x0 = (head == 0) ? q0 : (head == 1) ? k0
                    : (head == 2) ? v0 : s0;
  const unsigned ooff = (head == 0) ? 786432u
                        : (head == 1) ? 917504u
                        : (head == 2) ? 1048576u : 655360u;
  float v = hpart[idx] + hpart[524288u + idx] + hpart[1048576u + idx] +
            hpart[1572864u + idx] + b2[m * Kk + o];
  v = tanhf(fmaxf(v, 0.f));
  const float g = gates[(head * Mm + m) * Bb + b];
  const float x = x0[(m * Bb + b) * Kk + o];
  out[ooff + (m * Bb + b) * Kk + o] = g * v + (1.f - g) * x;
}

// ---------------------------------------------------------------------------
extern "C" void kernel_launch(void* const* d_in, const int* in_sizes, int n_in,
                              void* d_out, int out_size, void* d_ws,
                              size_t ws_size, hipStream_t stream) {
  (void)in_sizes; (void)n_in; (void)out_size; (void)ws_size;
  const float* s0  = (const float*)d_in[0];
  const float* q0  = (const float*)d_in[1];
  const float* k0  = (const float*)d_in[2];
  const float* v0  = (const float*)d_in[3];
  const float* key = (const float*)d_in[4];
  const float* val = (const float*)d_in[5];
  const float* wq  = (const float*)d_in[6];
  const float* wk  = (const float*)d_in[7];
  const float* wv  = (const float*)d_in[8];
  const float* bqa = (const float*)d_in[9];
  const float* bka = (const float*)d_in[10];
  const float* bva = (const float*)d_in[11];
  const float* wo  = (const float*)d_in[12];
  const float* bo  = (const float*)d_in[13];
  const float* qw1 = (const float*)d_in[14];
  const float* qb1 = (const float*)d_in[15];
  const float* qw2 = (const float*)d_in[16];
  const float* qb2 = (const float*)d_in[17];
  const float* kw1 = (const float*)d_in[18];
  const float* kb1 = (const float*)d_in[19];
  const float* kw2 = (const float*)d_in[20];
  const float* kb2 = (const float*)d_in[21];
  const float* vw1 = (const float*)d_in[22];
  const float* vb1 = (const float*)d_in[23];
  const float* vw2 = (const float*)d_in[24];
  const float* vb2 = (const float*)d_in[25];
  const float* sw1 = (const float*)d_in[26];
  const float* sb1 = (const float*)d_in[27];
  const float* sw2 = (const float*)d_in[28];
  const float* sb2 = (const float*)d_in[29];
  const float* gw1 = (const float*)d_in[30];
  const float* gb1 = (const float*)d_in[31];
  const float* gw2 = (const float*)d_in[32];
  const float* gb2 = (const float*)d_in[33];
  float* ws  = (float*)d_ws;
  float* out = (float*)d_out;

  k1_qproj<<<dim3(8, 8), 256, 0, stream>>>(q0, wq, bqa, ws + WS_Q);
  k2_uproj<<<dim3(8, 8), 256, 0, stream>>>(wk, bka, ws + WS_Q, ws + WS_U,
                                           ws + WS_QDB);
  k3_scores<<<dim3(64, 8), 256, 0, stream>>>(key, ws + WS_U, ws + WS_QDB,
                                             ws + WS_SC);
  k3b_softmax<<<dim3(8, 64), 256, 0, stream>>>(ws + WS_SC, out);
  k4a_av<<<dim3(64, 4, 2), 256, 0, stream>>>(val, ws + WS_SC, ws + WS_WPART);
  k5_ctx<<<dim3(8, 64), 256, 0, stream>>>(wv, bva, wo, bo, s0, ws + WS_WPART,
                                          out, ws + WS_FC);
  k6_mlp1<<<dim3(8, 8, 8), 256, 0, stream>>>(ws + WS_FC, qw1, kw1, vw1, sw1,
                                             gw1, qb1, kb1, vb1, sb1, gb1,
                                             ws + WS_H1);
  k6b_gates<<<dim3(32, 64), 64, 0, stream>>>(ws + WS_H1, gw2, gb2,
                                             ws + WS_GATES);
  k7a_mlp2<<<dim3(16, 8, 4), 256, 0, stream>>>(ws + WS_H1, qw2, kw2, vw2, sw2,
                                               ws + WS_HPART);
  k7b_final<<<dim3(2048), 256, 0, stream>>>(ws + WS_HPART, ws + WS_GATES, qb2,
                                            kb2, vb2, sb2, q0, k0, v0, s0,
                                            out);
}

// Round 4
// 444.754 us; speedup vs baseline: 1.1949x; 1.1949x over previous
//
#include <hip/hip_runtime.h>
#include <math.h>

// Problem dims
#define Mm 8
#define Bb 64
#define Ss 1024
#define Kk 256
#define Hh 8
#define HD 32
#define Ff 1024

typedef _Float16 f16x8 __attribute__((ext_vector_type(8)));
typedef float f32x4 __attribute__((ext_vector_type(4)));

// Workspace layout (float offsets), lifetimes disjoint where overlapped:
#define WS_Q      0u         // k1->k2, then FC (k5->k6)
#define WS_U      131072u    // k2->k3, then GATES at 262144
#define WS_QDB    1179648u   // k2->k3
#define WS_SC     1183744u   // k3->k4a/k3c, then HPART (k7a->k7b)
#define WS_W      5378048u   // k4a->k5 (1048576 floats)
#define WS_H1     6426624u   // k6->k6b/k7a (4194304 floats)
#define WS_FC     0u
#define WS_GATES  262144u
#define WS_HPART  1183744u
// total 10620928 floats = 42.5 MB (R0 kernel used this much: fits ws)

__device__ __forceinline__ unsigned pk2(float a, float b) {
  union { unsigned u; _Float16 h[2]; } c;
  c.h[0] = (_Float16)a; c.h[1] = (_Float16)b;
  return c.u;
}

// ---------------------------------------------------------------------------
// K1: q = q0 @ Wq + bq        (M,B,K)
__global__ __launch_bounds__(256) void k1_qproj(
    const float* __restrict__ q0, const float* __restrict__ wq,
    const float* __restrict__ bq, float* __restrict__ qout) {
  __shared__ float q0s[8 * 260];
  const int m = blockIdx.x, b0 = blockIdx.y * 8, t = threadIdx.x;
#pragma unroll
  for (int j = 0; j < 8; ++j)
    q0s[j * 260 + t] = q0[(m * Bb + b0 + j) * Kk + t];
  __syncthreads();
  float acc[8];
  const float bias = bq[m * Kk + t];
#pragma unroll
  for (int j = 0; j < 8; ++j) acc[j] = bias;
  const float* wcol = wq + m * Kk * Kk + t;
  for (int k4 = 0; k4 < Kk / 4; ++k4) {
    const float w0 = wcol[(k4 * 4 + 0) * Kk];
    const float w1 = wcol[(k4 * 4 + 1) * Kk];
    const float w2 = wcol[(k4 * 4 + 2) * Kk];
    const float w3 = wcol[(k4 * 4 + 3) * Kk];
#pragma unroll
    for (int j = 0; j < 8; ++j) {
      const float4 qv = *(const float4*)&q0s[j * 260 + k4 * 4];
      acc[j] += qv.x * w0 + qv.y * w1 + qv.z * w2 + qv.w * w3;
    }
  }
#pragma unroll
  for (int j = 0; j < 8; ++j)
    qout[(m * Bb + b0 + j) * Kk + t] = acc[j];
}

// ---------------------------------------------------------------------------
// K2: u(m,b,h,k) = sum_d Wk[m,k,h*32+d] * q[m,b,h*32+d]
__global__ __launch_bounds__(256) void k2_uproj(
    const float* __restrict__ wk, const float* __restrict__ bk,
    const float* __restrict__ q, float* __restrict__ u,
    float* __restrict__ qdb) {
  __shared__ float qs[64 * 36];
  const int m = blockIdx.x, h = blockIdx.y, t = threadIdx.x;
#pragma unroll
  for (int p = 0; p < 8; ++p) {
    const int idx = p * 256 + t;
    const int d = idx & 31, b = idx >> 5;
    qs[b * 36 + d] = q[(m * Bb + b) * Kk + h * HD + d];
  }
  __syncthreads();
  float acc[64];
#pragma unroll
  for (int b = 0; b < 64; ++b) acc[b] = 0.f;
  const float* wrow = wk + (m * Kk + t) * Kk + h * HD;
#pragma unroll
  for (int d4 = 0; d4 < 8; ++d4) {
    const float4 w4 = *(const float4*)&wrow[d4 * 4];
#pragma unroll
    for (int b = 0; b < 64; ++b) {
      const float4 q4 = *(const float4*)&qs[b * 36 + d4 * 4];
      acc[b] += q4.x * w4.x + q4.y * w4.y + q4.z * w4.z + q4.w * w4.w;
    }
  }
  for (int b = 0; b < 64; ++b)
    u[((m * Bb + b) * Hh + h) * Kk + t] = acc[b];
  if (t < 64) {
    float s = 0.f;
#pragma unroll
    for (int d = 0; d < 32; ++d)
      s += qs[t * 36 + d] * bk[m * Kk + h * HD + d];
    qdb[(m * Bb + t) * Hh + h] = s;
  }
}

// ---------------------------------------------------------------------------
// K3 (fp16 MFMA, dbuf): scores(m,b,h,s) = (key·u + qdb)/sqrt(32)
// grid (64, 16): (b, s-tile of 64). 4 waves; wave w = mh-tile w; 4 s-frags.
// LDS tiles packed fp16-pair u32, row stride 20 u32 (80B, 16B-aligned).
__global__ __launch_bounds__(256) void k3_scores(
    const float* __restrict__ key, const float* __restrict__ u,
    const float* __restrict__ qdb, float* __restrict__ sc) {
  __shared__ unsigned Us[2][64 * 20];
  __shared__ unsigned Ks[2][64 * 20];
  __shared__ float qd[64];
  const int b = blockIdx.x, st0 = blockIdx.y * 64, t = threadIdx.x;
  const int w = t >> 6, lane = t & 63, quad = lane >> 4, l15 = lane & 15;
  if (t < 64) qd[t] = qdb[((t >> 3) * Bb + b) * Hh + (t & 7)];
  // U staging: 4 lanes/row, 8 floats each
  const int umh = t >> 2, ukg = t & 3;
  const float* ug =
      u + (((umh >> 3) * Bb + b) * Hh + (umh & 7)) * Kk + ukg * 8;
  // K staging: same shape over 64 s-rows
  const int ksr = t >> 2, kkg = t & 3;
  const float* kg =
      key + (size_t)(st0 + ksr) * (Bb * Kk) + b * Kk + kkg * 8;
  float4 pu[2][2], pkv[2][2];
  f32x4 acc[4];
#pragma unroll
  for (int i = 0; i < 4; ++i) acc[i] = (f32x4){0.f, 0.f, 0.f, 0.f};

#define K3_LOAD(c, s)                                   \
  {                                                     \
    pu[s][0] = *(const float4*)(ug + (c) * 32);         \
    pu[s][1] = *(const float4*)(ug + (c) * 32 + 4);     \
    pkv[s][0] = *(const float4*)(kg + (c) * 32);        \
    pkv[s][1] = *(const float4*)(kg + (c) * 32 + 4);    \
  }
#define K3_STORE(buf, s)                                                   \
  {                                                                        \
    uint4 v;                                                               \
    v.x = pk2(pu[s][0].x, pu[s][0].y); v.y = pk2(pu[s][0].z, pu[s][0].w);  \
    v.z = pk2(pu[s][1].x, pu[s][1].y); v.w = pk2(pu[s][1].z, pu[s][1].w);  \
    *(uint4*)&Us[buf][umh * 20 + ukg * 4] = v;                             \
    uint4 q_;                                                              \
    q_.x = pk2(pkv[s][0].x, pkv[s][0].y);                                  \
    q_.y = pk2(pkv[s][0].z, pkv[s][0].w);                                  \
    q_.z = pk2(pkv[s][1].x, pkv[s][1].y);                                  \
    q_.w = pk2(pkv[s][1].z, pkv[s][1].w);                                  \
    *(uint4*)&Ks[buf][ksr * 20 + kkg * 4] = q_;                            \
  }

  K3_LOAD(0, 0); K3_STORE(0, 0);
  K3_LOAD(1, 1);
#pragma unroll
  for (int c = 0; c < 8; ++c) {
    __syncthreads();
    if (c + 2 < 8) K3_LOAD(c + 2, c & 1);
    const f16x8 af = *(const f16x8*)&Us[c & 1][(w * 16 + l15) * 20 + quad * 4];
#pragma unroll
    for (int sf = 0; sf < 4; ++sf) {
      const f16x8 bf =
          *(const f16x8*)&Ks[c & 1][(sf * 16 + l15) * 20 + quad * 4];
      acc[sf] =
          __builtin_amdgcn_mfma_f32_16x16x32_f16(af, bf, acc[sf], 0, 0, 0);
    }
    if (c + 1 < 8) K3_STORE((c + 1) & 1, (c + 1) & 1);
  }
  const float scale = 0.17677669529663687f;  // 1/sqrt(32)
#pragma unroll
  for (int sf = 0; sf < 4; ++sf) {
    const int s = st0 + sf * 16 + l15;
#pragma unroll
    for (int r = 0; r < 4; ++r) {
      const int mh = w * 16 + quad * 4 + r;
      sc[(size_t)(((mh >> 3) * Bb + b) * Hh + (mh & 7)) * Ss + s] =
          (acc[sf][r] + qd[mh]) * scale;
    }
  }
#undef K3_LOAD
#undef K3_STORE
}

// ---------------------------------------------------------------------------
// K3b: softmax over s, one block per (m,b,h) row. grid 4096.
__global__ __launch_bounds__(256) void k3b_softmax(float* __restrict__ sc) {
  __shared__ float red[8];
  const int row = blockIdx.x, t = threadIdx.x;
  const int lane = t & 63, wid = t >> 6;
  float4 v = *(const float4*)&sc[(size_t)row * 1024 + t * 4];
  float mx = fmaxf(fmaxf(v.x, v.y), fmaxf(v.z, v.w));
  for (int off = 32; off > 0; off >>= 1)
    mx = fmaxf(mx, __shfl_down(mx, off, 64));
  if (lane == 0) red[wid] = mx;
  __syncthreads();
  mx = fmaxf(fmaxf(red[0], red[1]), fmaxf(red[2], red[3]));
  v.x = __expf(v.x - mx); v.y = __expf(v.y - mx);
  v.z = __expf(v.z - mx); v.w = __expf(v.w - mx);
  float sm = v.x + v.y + v.z + v.w;
  for (int off = 32; off > 0; off >>= 1) sm += __shfl_down(sm, off, 64);
  if (lane == 0) red[4 + wid] = sm;
  __syncthreads();
  const float inv = 1.f / (red[4] + red[5] + red[6] + red[7]);
  v.x *= inv; v.y *= inv; v.z *= inv; v.w *= inv;
  *(float4*)&sc[(size_t)row * 1024 + t * 4] = v;
}

// ---------------------------------------------------------------------------
// K3c: attn_weights = mean over h. grid (8, 64): (m, b).
__global__ __launch_bounds__(256) void k3c_awmean(
    const float* __restrict__ sc, float* __restrict__ out) {
  const int m = blockIdx.x, b = blockIdx.y, t = threadIdx.x;
  const size_t base = (size_t)(m * Bb + b) * (Hh * Ss);
#pragma unroll
  for (int p = 0; p < 4; ++p) {
    const int s = p * 256 + t;
    float sum = 0.f;
#pragma unroll
    for (int h = 0; h < 8; ++h) sum += sc[base + h * 1024 + s];
    out[131072u + (m * Bb + b) * Ss + s] = sum * 0.125f;
  }
}

// ---------------------------------------------------------------------------
// K4a (fp16 MFMA, dbuf): w(m,b,h,k) = sum_s aw(m,b,h,s)*value(s,b,k)
// grid (64, 8): (b, k-slice of 32). Full s=1024 per block -> writes w direct.
// Same-b blocks land on the same XCD (stride 64 = 0 mod 8) -> aw L2 reuse.
__global__ __launch_bounds__(256) void k4a_av(const float* __restrict__ value,
                                              const float* __restrict__ aw,
                                              float* __restrict__ wout) {
  __shared__ unsigned Ap[2][64 * 20];  // aw packed   [mh][sp]
  __shared__ unsigned Vp[2][32 * 20];  // value^T pk  [k][sp]
  const int b = blockIdx.x, ko = blockIdx.y, t = threadIdx.x;
  const int w = t >> 6, lane = t & 63, quad = lane >> 4, l15 = lane & 15;
  const int amh = t >> 2, asg = t & 3;
  const float* ag =
      aw + ((size_t)((amh >> 3) * Bb + b) * Hh + (amh & 7)) * Ss + asg * 8;
  const int vk = (t & 15) * 2, vsp = t >> 4;  // s-pair = 2*vsp within chunk
  const float* vg = value + (size_t)(2 * vsp) * (Bb * Kk) + b * Kk +
                    ko * 32 + vk;
  const size_t srow = (size_t)(Bb * Kk);
  float4 pa[2][2];
  float2 pv[2][2];
  f32x4 acc[2];
  acc[0] = (f32x4){0.f, 0.f, 0.f, 0.f};
  acc[1] = (f32x4){0.f, 0.f, 0.f, 0.f};

#define K4_LOAD(c, s)                                         \
  {                                                           \
    pa[s][0] = *(const float4*)(ag + (c) * 32);               \
    pa[s][1] = *(const float4*)(ag + (c) * 32 + 4);           \
    const float* vb = vg + (size_t)(c) * 32 * srow;           \
    pv[s][0] = *(const float2*)vb;                            \
    pv[s][1] = *(const float2*)(vb + srow);                   \
  }
#define K4_STORE(buf, s)                                                   \
  {                                                                        \
    uint4 v;                                                               \
    v.x = pk2(pa[s][0].x, pa[s][0].y); v.y = pk2(pa[s][0].z, pa[s][0].w);  \
    v.z = pk2(pa[s][1].x, pa[s][1].y); v.w = pk2(pa[s][1].z, pa[s][1].w);  \
    *(uint4*)&Ap[buf][amh * 20 + asg * 4] = v;                             \
    Vp[buf][vk * 20 + vsp] = pk2(pv[s][0].x, pv[s][1].x);                  \
    Vp[buf][(vk + 1) * 20 + vsp] = pk2(pv[s][0].y, pv[s][1].y);            \
  }

  K4_LOAD(0, 0); K4_STORE(0, 0);
  K4_LOAD(1, 1);
#pragma unroll
  for (int c = 0; c < 32; ++c) {
    __syncthreads();
    if (c + 2 < 32) K4_LOAD(c + 2, c & 1);
    const f16x8 af = *(const f16x8*)&Ap[c & 1][(w * 16 + l15) * 20 + quad * 4];
#pragma unroll
    for (int nt = 0; nt < 2; ++nt) {
      const f16x8 bf =
          *(const f16x8*)&Vp[c & 1][(nt * 16 + l15) * 20 + quad * 4];
      acc[nt] =
          __builtin_amdgcn_mfma_f32_16x16x32_f16(af, bf, acc[nt], 0, 0, 0);
    }
    if (c + 1 < 32) K4_STORE((c + 1) & 1, (c + 1) & 1);
  }
#pragma unroll
  for (int nt = 0; nt < 2; ++nt) {
    const int k = ko * 32 + nt * 16 + l15;
#pragma unroll
    for (int r = 0; r < 4; ++r) {
      const int mh = w * 16 + quad * 4 + r;
      wout[((size_t)((mh >> 3) * Bb + b) * Hh + (mh & 7)) * Kk + k] =
          acc[nt][r];
    }
  }
#undef K4_LOAD
#undef K4_STORE
}

// ---------------------------------------------------------------------------
// K5: ctx = w @ Wv_h + bv ; attn_out = ctx @ Wo + bo ; fc_in = relu(concat)
__global__ __launch_bounds__(256) void k5_ctx(
    const float* __restrict__ wv, const float* __restrict__ bv,
    const float* __restrict__ wo, const float* __restrict__ bo,
    const float* __restrict__ s0in, const float* __restrict__ w,
    float* __restrict__ attn_out, float* __restrict__ fc) {
  __shared__ float wsh[2048];
  __shared__ float ctxs[256];
  const int m = blockIdx.x, b = blockIdx.y, t = threadIdx.x;
  const int base = (m * Bb + b) * (Hh * Kk);
#pragma unroll
  for (int p = 0; p < 8; ++p) wsh[p * 256 + t] = w[base + p * 256 + t];
  __syncthreads();
  const int h = t >> 5;
  float acc = bv[m * Kk + t];
  const float* wvc = wv + m * Kk * Kk + t;
  for (int k4 = 0; k4 < 64; ++k4) {
    const float4 a4 = *(const float4*)&wsh[h * 256 + k4 * 4];
    acc += a4.x * wvc[(k4 * 4 + 0) * Kk] + a4.y * wvc[(k4 * 4 + 1) * Kk] +
           a4.z * wvc[(k4 * 4 + 2) * Kk] + a4.w * wvc[(k4 * 4 + 3) * Kk];
  }
  ctxs[t] = acc;
  __syncthreads();
  float acc2 = bo[m * Kk + t];
  const float* woc = wo + m * Kk * Kk + t;
  for (int k4 = 0; k4 < 64; ++k4) {
    const float4 c4 = *(const float4*)&ctxs[k4 * 4];
    acc2 += c4.x * woc[(k4 * 4 + 0) * Kk] + c4.y * woc[(k4 * 4 + 1) * Kk] +
            c4.z * woc[(k4 * 4 + 2) * Kk] + c4.w * woc[(k4 * 4 + 3) * Kk];
  }
  const int ob = (m * Bb + b) * Kk + t;
  attn_out[ob] = acc2;
  fc[(m * Bb + b) * 512 + t] = fmaxf(acc2, 0.f);
  fc[(m * Bb + b) * 512 + 256 + t] = fmaxf(s0in[ob], 0.f);
}

// ---------------------------------------------------------------------------
// K6 (fp16 MFMA, dbuf): h1[head] = relu(fc_in @ W1[head] + b1[head])
// grid (16, 8, 8): (f-tile of 64, m, head). 4 waves; wave w = f-subtile w.
__global__ __launch_bounds__(256) void k6_mlp1(
    const float* __restrict__ fc, const float* __restrict__ w1q,
    const float* __restrict__ w1k, const float* __restrict__ w1v,
    const float* __restrict__ w1s, const float* __restrict__ w1g,
    const float* __restrict__ b1q, const float* __restrict__ b1k,
    const float* __restrict__ b1v, const float* __restrict__ b1s,
    const float* __restrict__ b1g, float* __restrict__ h1) {
  __shared__ unsigned As[2][64 * 20];  // fc packed  [b][kp]
  __shared__ unsigned Ws[2][64 * 20];  // W1^T packed[f][kp]
  const int ft = blockIdx.x, m = blockIdx.y, head = blockIdx.z,
            t = threadIdx.x;
  const float* w1;
  const float* b1;
  if (head == 0)      { w1 = w1q; b1 = b1q; }
  else if (head == 1) { w1 = w1k; b1 = b1k; }
  else if (head == 2) { w1 = w1v; b1 = b1v; }
  else if (head == 3) { w1 = w1s; b1 = b1s; }
  else {
    w1 = w1g + (size_t)(head - 4) * (Mm * 512 * Ff);
    b1 = b1g + (head - 4) * (Mm * Ff);
  }
  w1 += (size_t)m * 512 * Ff;
  b1 += m * Ff;
  const int w = t >> 6, lane = t & 63, quad = lane >> 4, l15 = lane & 15;
  const int abb = t >> 2, akg = t & 3;
  const float* ag = fc + (m * Bb + abb) * 512 + akg * 8;
  const int wf0 = (t & 15) * 4, wkp = t >> 4;
  const float* wg = w1 + (size_t)(2 * wkp) * Ff + ft * 64 + wf0;
  float4 pa[2][2], pw[2][2];
  f32x4 acc[4];
#pragma unroll
  for (int i = 0; i < 4; ++i) acc[i] = (f32x4){0.f, 0.f, 0.f, 0.f};

#define K6_LOAD(c, s)                                            \
  {                                                              \
    pa[s][0] = *(const float4*)(ag + (c) * 32);                  \
    pa[s][1] = *(const float4*)(ag + (c) * 32 + 4);              \
    const float* wb = wg + (size_t)(c) * 32 * Ff;                \
    pw[s][0] = *(const float4*)wb;                               \
    pw[s][1] = *(const float4*)(wb + Ff);                        \
  }
#define K6_STORE(buf, s)                                                   \
  {                                                                        \
    uint4 v;                                                               \
    v.x = pk2(pa[s][0].x, pa[s][0].y); v.y = pk2(pa[s][0].z, pa[s][0].w);  \
    v.z = pk2(pa[s][1].x, pa[s][1].y); v.w = pk2(pa[s][1].z, pa[s][1].w);  \
    *(uint4*)&As[buf][abb * 20 + akg * 4] = v;                             \
    Ws[buf][(wf0 + 0) * 20 + wkp] = pk2(pw[s][0].x, pw[s][1].x);           \
    Ws[buf][(wf0 + 1) * 20 + wkp] = pk2(pw[s][0].y, pw[s][1].y);           \
    Ws[buf][(wf0 + 2) * 20 + wkp] = pk2(pw[s][0].z, pw[s][1].z);           \
    Ws[buf][(wf0 + 3) * 20 + wkp] = pk2(pw[s][0].w, pw[s][1].w);           \
  }

  K6_LOAD(0, 0); K6_STORE(0, 0);
  K6_LOAD(1, 1);
#pragma unroll
  for (int c = 0; c < 16; ++c) {
    __syncthreads();
    if (c + 2 < 16) K6_LOAD(c + 2, c & 1);
    const f16x8 bf = *(const f16x8*)&Ws[c & 1][(w * 16 + l15) * 20 + quad * 4];
#pragma unroll
    for (int mt = 0; mt < 4; ++mt) {
      const f16x8 af =
          *(const f16x8*)&As[c & 1][(mt * 16 + l15) * 20 + quad * 4];
      acc[mt] =
          __builtin_amdgcn_mfma_f32_16x16x32_f16(af, bf, acc[mt], 0, 0, 0);
    }
    if (c + 1 < 16) K6_STORE((c + 1) & 1, (c + 1) & 1);
  }
  const int f = ft * 64 + w * 16 + l15;
  const float bias = b1[f];
  float* hb = h1 + (size_t)((head * Mm + m) * Bb) * Ff + f;
#pragma unroll
  for (int mt = 0; mt < 4; ++mt) {
#pragma unroll
    for (int r = 0; r < 4; ++r) {
      const int bb = mt * 16 + quad * 4 + r;
      hb[(size_t)bb * Ff] = fmaxf(acc[mt][r] + bias, 0.f);
    }
  }
#undef K6_LOAD
#undef K6_STORE
}

// ---------------------------------------------------------------------------
// K6b: gates(g,m,b) = sigmoid(h1[4+g,m,b,:] . g_w2[g,m,:] + g_b2[g,m])
__global__ __launch_bounds__(64) void k6b_gates(
    const float* __restrict__ h1, const float* __restrict__ gw2,
    const float* __restrict__ gb2, float* __restrict__ gates) {
  const int gm = blockIdx.x, b = blockIdx.y, t = threadIdx.x;
  const int g = gm >> 3, m = gm & 7;
  const float* hrow = h1 + (size_t)(((4 + g) * Mm + m) * Bb + b) * Ff;
  const float* wrow = gw2 + (g * Mm + m) * Ff;
  float s = 0.f;
#pragma unroll
  for (int i = 0; i < 16; ++i) s += hrow[t + i * 64] * wrow[t + i * 64];
  for (int off = 32; off > 0; off >>= 1) s += __shfl_down(s, off, 64);
  if (t == 0)
    gates[(g * Mm + m) * Bb + b] =
        1.f / (1.f + __expf(-(s + gb2[g * Mm + m])));
}

// ---------------------------------------------------------------------------
// K7a: partial second-layer head outputs over an f-quarter (K=256)
__global__ __launch_bounds__(256) void k7a_mlp2(
    const float* __restrict__ h1, const float* __restrict__ w2q,
    const float* __restrict__ w2k, const float* __restrict__ w2v,
    const float* __restrict__ w2s, float* __restrict__ hpart) {
  __shared__ float Ht[32 * 68];
  __shared__ float Wt[32 * 68];
  const int fq = blockIdx.x >> 2, oc = blockIdx.x & 3;
  const int m = blockIdx.y, head = blockIdx.z, t = threadIdx.x;
  const float* w2 =
      (head == 0) ? w2q : (head == 1) ? w2k : (head == 2) ? w2v : w2s;
  w2 += (size_t)m * Ff * Kk;
  const float* hbase = h1 + (size_t)((head * Mm + m) * Bb) * Ff + fq * 256;
  const int to = t & 15, tb = t >> 4;
  float acc[4][4];
#pragma unroll
  for (int j = 0; j < 4; ++j)
#pragma unroll
    for (int i = 0; i < 4; ++i) acc[j][i] = 0.f;
  for (int it = 0; it < 8; ++it) {
    __syncthreads();
#pragma unroll
    for (int p = 0; p < 8; ++p) {
      const int idx = p * 256 + t;
      const int f = idx & 31, bb = idx >> 5;
      Ht[f * 68 + bb] = hbase[bb * Ff + it * 32 + f];
    }
#pragma unroll
    for (int p = 0; p < 8; ++p) {
      const int idx = p * 256 + t;
      const int o = idx & 63, f = idx >> 6;
      Wt[f * 68 + o] = w2[(fq * 256 + it * 32 + f) * Kk + oc * 64 + o];
    }
    __syncthreads();
#pragma unroll 8
    for (int kk = 0; kk < 32; ++kk) {
      const float4 a4 = *(const float4*)&Ht[kk * 68 + tb * 4];
      const float4 w4 = *(const float4*)&Wt[kk * 68 + to * 4];
      acc[0][0] += a4.x * w4.x; acc[0][1] += a4.x * w4.y;
      acc[0][2] += a4.x * w4.z; acc[0][3] += a4.x * w4.w;
      acc[1][0] += a4.y * w4.x; acc[1][1] += a4.y * w4.y;
      acc[1][2] += a4.y * w4.z; acc[1][3] += a4.y * w4.w;
      acc[2][0] += a4.z * w4.x; acc[2][1] += a4.z * w4.y;
      acc[2][2] += a4.z * w4.z; acc[2][3] += a4.z * w4.w;
      acc[3][0] += a4.w * w4.x; acc[3][1] += a4.w * w4.y;
      acc[3][2] += a4.w * w4.z; acc[3][3] += a4.w * w4.w;
    }
  }
  float* hp =
      hpart + fq * 524288u + (size_t)((head * Mm + m) * Bb) * Kk + oc * 64;
#pragma unroll
  for (int j = 0; j < 4; ++j) {
    const int bb = tb * 4 + j;
    float4 r = {acc[j][0], acc[j][1], acc[j][2], acc[j][3]};
    *(float4*)&hp[bb * Kk + to * 4] = r;
  }
}

// ---------------------------------------------------------------------------
// K7b: out = gate*tanh(relu(p0+p1+p2+p3+b2)) + (1-gate)*x0
__global__ __launch_bounds__(256) void k7b_final(
    const float* __restrict__ hpart, const float* __restrict__ gates,
    const float* __restrict__ b2q, const float* __restrict__ b2k,
    const float* __restrict__ b2v, const float* __restrict__ b2s,
    const float* __restrict__ q0, const float* __restrict__ k0,
    const float* __restrict__ v0, const float* __restrict__ s0,
    float* __restrict__ out) {
  const int idx = blockIdx.x * 256 + threadIdx.x;
  const int o = idx & 255;
  const int b = (idx >> 8) & 63;
  const int m = (idx >> 14) & 7;
  const int head = idx >> 17;
  const float* b2 = (head == 0) ? b2q : (head == 1) ? b2k
                    : (head == 2) ? b2v : b2s;
  const float* x0 = (head == 0) ? q0 : (head == 1) ? k0
                    : (head == 2) ? v0 : s0;
  const unsigned ooff = (head == 0) ? 786432u
                        : (head == 1) ? 917504u
                        : (head == 2) ? 1048576u : 655360u;
  float v = hpart[idx] + hpart[524288u + idx] + hpart[1048576u + idx] +
            hpart[1572864u + idx] + b2[m * Kk + o];
  v = tanhf(fmaxf(v, 0.f));
  const float g = gates[(head * Mm + m) * Bb + b];
  const float x = x0[(m * Bb + b) * Kk + o];
  out[ooff + (m * Bb + b) * Kk + o] = g * v + (1.f - g) * x;
}

// ---------------------------------------------------------------------------
extern "C" void kernel_launch(void* const* d_in, const int* in_sizes, int n_in,
                              void* d_out, int out_size, void* d_ws,
                              size_t ws_size, hipStream_t stream) {
  (void)in_sizes; (void)n_in; (void)out_size; (void)ws_size;
  const float* s0  = (const float*)d_in[0];
  const float* q0  = (const float*)d_in[1];
  const float* k0  = (const float*)d_in[2];
  const float* v0  = (const float*)d_in[3];
  const float* key = (const float*)d_in[4];
  const float* val = (const float*)d_in[5];
  const float* wq  = (const float*)d_in[6];
  const float* wk  = (const float*)d_in[7];
  const float* wv  = (const float*)d_in[8];
  const float* bqa = (const float*)d_in[9];
  const float* bka = (const float*)d_in[10];
  const float* bva = (const float*)d_in[11];
  const float* wo  = (const float*)d_in[12];
  const float* bo  = (const float*)d_in[13];
  const float* qw1 = (const float*)d_in[14];
  const float* qb1 = (const float*)d_in[15];
  const float* qw2 = (const float*)d_in[16];
  const float* qb2 = (const float*)d_in[17];
  const float* kw1 = (const float*)d_in[18];
  const float* kb1 = (const float*)d_in[19];
  const float* kw2 = (const float*)d_in[20];
  const float* kb2 = (const float*)d_in[21];
  const float* vw1 = (const float*)d_in[22];
  const float* vb1 = (const float*)d_in[23];
  const float* vw2 = (const float*)d_in[24];
  const float* vb2 = (const float*)d_in[25];
  const float* sw1 = (const float*)d_in[26];
  const float* sb1 = (const float*)d_in[27];
  const float* sw2 = (const float*)d_in[28];
  const float* sb2 = (const float*)d_in[29];
  const float* gw1 = (const float*)d_in[30];
  const float* gb1 = (const float*)d_in[31];
  const float* gw2 = (const float*)d_in[32];
  const float* gb2 = (const float*)d_in[33];
  float* ws  = (float*)d_ws;
  float* out = (float*)d_out;

  k1_qproj<<<dim3(8, 8), 256, 0, stream>>>(q0, wq, bqa, ws + WS_Q);
  k2_uproj<<<dim3(8, 8), 256, 0, stream>>>(wk, bka, ws + WS_Q, ws + WS_U,
                                           ws + WS_QDB);
  k3_scores<<<dim3(64, 16), 256, 0, stream>>>(key, ws + WS_U, ws + WS_QDB,
                                              ws + WS_SC);
  k3b_softmax<<<dim3(4096), 256, 0, stream>>>(ws + WS_SC);
  k3c_awmean<<<dim3(8, 64), 256, 0, stream>>>(ws + WS_SC, out);
  k4a_av<<<dim3(64, 8), 256, 0, stream>>>(val, ws + WS_SC, ws + WS_W);
  k5_ctx<<<dim3(8, 64), 256, 0, stream>>>(wv, bva, wo, bo, s0, ws + WS_W, out,
                                          ws + WS_FC);
  k6_mlp1<<<dim3(16, 8, 8), 256, 0, stream>>>(ws + WS_FC, qw1, kw1, vw1, sw1,
                                              gw1, qb1, kb1, vb1, sb1, gb1,
                                              ws + WS_H1);
  k6b_gates<<<dim3(32, 64), 64, 0, stream>>>(ws + WS_H1, gw2, gb2,
                                             ws + WS_GATES);
  k7a_mlp2<<<dim3(16, 8, 4), 256, 0, stream>>>(ws + WS_H1, qw2, kw2, vw2, sw2,
                                               ws + WS_HPART);
  k7b_final<<<dim3(2048), 256, 0, stream>>>(ws + WS_HPART, ws + WS_GATES, qb2,
                                            kb2, vb2, sb2, q0, k0, v0, s0,
                                            out);
}

// Round 5
// 426.065 us; speedup vs baseline: 1.2473x; 1.0439x over previous
//
#include <hip/hip_runtime.h>
#include <math.h>

// Problem dims
#define Mm 8
#define Bb 64
#define Ss 1024
#define Kk 256
#define Hh 8
#define HD 32
#define Ff 1024

typedef _Float16 f16x8 __attribute__((ext_vector_type(8)));
typedef float f32x4 __attribute__((ext_vector_type(4)));

// Workspace layout (float offsets), lifetimes disjoint where overlapped:
#define WS_Q      0u         // k1->k2, then FC (k5->k6)
#define WS_U      131072u    // k2->k3, then GATES at 262144
#define WS_QDB    1179648u   // k2->k3
#define WS_SC     1183744u   // k3->k4a, then HPART (k7a->k7b)
#define WS_W      5378048u   // k4a->k5 (1048576 floats)
#define WS_H1     6426624u   // k6->k6b/k7a (4194304 floats)
#define WS_FC     0u
#define WS_GATES  262144u
#define WS_HPART  1183744u

__device__ __forceinline__ unsigned pk2(float a, float b) {
  union { unsigned u; _Float16 h[2]; } c;
  c.h[0] = (_Float16)a; c.h[1] = (_Float16)b;
  return c.u;
}

// ---------------------------------------------------------------------------
// K1: q = q0 @ Wq + bq        (M,B,K)
__global__ __launch_bounds__(256) void k1_qproj(
    const float* __restrict__ q0, const float* __restrict__ wq,
    const float* __restrict__ bq, float* __restrict__ qout) {
  __shared__ float q0s[8 * 260];
  const int m = blockIdx.x, b0 = blockIdx.y * 8, t = threadIdx.x;
#pragma unroll
  for (int j = 0; j < 8; ++j)
    q0s[j * 260 + t] = q0[(m * Bb + b0 + j) * Kk + t];
  __syncthreads();
  float acc[8];
  const float bias = bq[m * Kk + t];
#pragma unroll
  for (int j = 0; j < 8; ++j) acc[j] = bias;
  const float* wcol = wq + m * Kk * Kk + t;
  for (int k4 = 0; k4 < Kk / 4; ++k4) {
    const float w0 = wcol[(k4 * 4 + 0) * Kk];
    const float w1 = wcol[(k4 * 4 + 1) * Kk];
    const float w2 = wcol[(k4 * 4 + 2) * Kk];
    const float w3 = wcol[(k4 * 4 + 3) * Kk];
#pragma unroll
    for (int j = 0; j < 8; ++j) {
      const float4 qv = *(const float4*)&q0s[j * 260 + k4 * 4];
      acc[j] += qv.x * w0 + qv.y * w1 + qv.z * w2 + qv.w * w3;
    }
  }
#pragma unroll
  for (int j = 0; j < 8; ++j)
    qout[(m * Bb + b0 + j) * Kk + t] = acc[j];
}

// ---------------------------------------------------------------------------
// K2: u(m,b,h,k) = sum_d Wk[m,k,h*32+d] * q[m,b,h*32+d]
__global__ __launch_bounds__(256) void k2_uproj(
    const float* __restrict__ wk, const float* __restrict__ bk,
    const float* __restrict__ q, float* __restrict__ u,
    float* __restrict__ qdb) {
  __shared__ float qs[64 * 36];
  const int m = blockIdx.x, h = blockIdx.y, t = threadIdx.x;
#pragma unroll
  for (int p = 0; p < 8; ++p) {
    const int idx = p * 256 + t;
    const int d = idx & 31, b = idx >> 5;
    qs[b * 36 + d] = q[(m * Bb + b) * Kk + h * HD + d];
  }
  __syncthreads();
  float acc[64];
#pragma unroll
  for (int b = 0; b < 64; ++b) acc[b] = 0.f;
  const float* wrow = wk + (m * Kk + t) * Kk + h * HD;
#pragma unroll
  for (int d4 = 0; d4 < 8; ++d4) {
    const float4 w4 = *(const float4*)&wrow[d4 * 4];
#pragma unroll
    for (int b = 0; b < 64; ++b) {
      const float4 q4 = *(const float4*)&qs[b * 36 + d4 * 4];
      acc[b] += q4.x * w4.x + q4.y * w4.y + q4.z * w4.z + q4.w * w4.w;
    }
  }
  for (int b = 0; b < 64; ++b)
    u[((m * Bb + b) * Hh + h) * Kk + t] = acc[b];
  if (t < 64) {
    float s = 0.f;
#pragma unroll
    for (int d = 0; d < 32; ++d)
      s += qs[t * 36 + d] * bk[m * Kk + h * HD + d];
    qdb[(m * Bb + t) * Hh + h] = s;
  }
}

// ---------------------------------------------------------------------------
// K3 (fp16 MFMA, dbuf): scores(m,b,h,s) = (key·u + qdb)/sqrt(32)
__global__ __launch_bounds__(256) void k3_scores(
    const float* __restrict__ key, const float* __restrict__ u,
    const float* __restrict__ qdb, float* __restrict__ sc) {
  __shared__ unsigned Us[2][64 * 20];
  __shared__ unsigned Ks[2][64 * 20];
  __shared__ float qd[64];
  const int b = blockIdx.x, st0 = blockIdx.y * 64, t = threadIdx.x;
  const int w = t >> 6, lane = t & 63, quad = lane >> 4, l15 = lane & 15;
  if (t < 64) qd[t] = qdb[((t >> 3) * Bb + b) * Hh + (t & 7)];
  const int umh = t >> 2, ukg = t & 3;
  const float* ug =
      u + (((umh >> 3) * Bb + b) * Hh + (umh & 7)) * Kk + ukg * 8;
  const int ksr = t >> 2, kkg = t & 3;
  const float* kg =
      key + (size_t)(st0 + ksr) * (Bb * Kk) + b * Kk + kkg * 8;
  float4 pu[2][2], pkv[2][2];
  f32x4 acc[4];
#pragma unroll
  for (int i = 0; i < 4; ++i) acc[i] = (f32x4){0.f, 0.f, 0.f, 0.f};

#define K3_LOAD(c, s)                                   \
  {                                                     \
    pu[s][0] = *(const float4*)(ug + (c) * 32);         \
    pu[s][1] = *(const float4*)(ug + (c) * 32 + 4);     \
    pkv[s][0] = *(const float4*)(kg + (c) * 32);        \
    pkv[s][1] = *(const float4*)(kg + (c) * 32 + 4);    \
  }
#define K3_STORE(buf, s)                                                   \
  {                                                                        \
    uint4 v;                                                               \
    v.x = pk2(pu[s][0].x, pu[s][0].y); v.y = pk2(pu[s][0].z, pu[s][0].w);  \
    v.z = pk2(pu[s][1].x, pu[s][1].y); v.w = pk2(pu[s][1].z, pu[s][1].w);  \
    *(uint4*)&Us[buf][umh * 20 + ukg * 4] = v;                             \
    uint4 q_;                                                              \
    q_.x = pk2(pkv[s][0].x, pkv[s][0].y);                                  \
    q_.y = pk2(pkv[s][0].z, pkv[s][0].w);                                  \
    q_.z = pk2(pkv[s][1].x, pkv[s][1].y);                                  \
    q_.w = pk2(pkv[s][1].z, pkv[s][1].w);                                  \
    *(uint4*)&Ks[buf][ksr * 20 + kkg * 4] = q_;                            \
  }

  K3_LOAD(0, 0); K3_STORE(0, 0);
  K3_LOAD(1, 1);
#pragma unroll
  for (int c = 0; c < 8; ++c) {
    __syncthreads();
    if (c + 2 < 8) K3_LOAD(c + 2, c & 1);
    const f16x8 af = *(const f16x8*)&Us[c & 1][(w * 16 + l15) * 20 + quad * 4];
#pragma unroll
    for (int sf = 0; sf < 4; ++sf) {
      const f16x8 bf =
          *(const f16x8*)&Ks[c & 1][(sf * 16 + l15) * 20 + quad * 4];
      acc[sf] =
          __builtin_amdgcn_mfma_f32_16x16x32_f16(af, bf, acc[sf], 0, 0, 0);
    }
    if (c + 1 < 8) K3_STORE((c + 1) & 1, (c + 1) & 1);
  }
  const float scale = 0.17677669529663687f;  // 1/sqrt(32)
#pragma unroll
  for (int sf = 0; sf < 4; ++sf) {
    const int s = st0 + sf * 16 + l15;
#pragma unroll
    for (int r = 0; r < 4; ++r) {
      const int mh = w * 16 + quad * 4 + r;
      sc[(size_t)(((mh >> 3) * Bb + b) * Hh + (mh & 7)) * Ss + s] =
          (acc[sf][r] + qd[mh]) * scale;
    }
  }
#undef K3_LOAD
#undef K3_STORE
}

// ---------------------------------------------------------------------------
// K3b: softmax over s per (m,b,h) AND attn_weights mean-over-h, fused.
// grid (8, 64): (m, b), 256 threads = 4 waves; wave w handles h = 2w, 2w+1.
// Softmax is wave-local (row of 1024 = 64 lanes x 16): shuffle-only.
__global__ __launch_bounds__(256) void k3b_softmax(float* __restrict__ sc,
                                                   float* __restrict__ out) {
  __shared__ float rows[8 * 1024];
  const int m = blockIdx.x, b = blockIdx.y, t = threadIdx.x;
  const int w = t >> 6, lane = t & 63;
  const size_t base = (size_t)(m * Bb + b) * (Hh * Ss);
#pragma unroll
  for (int hh = 0; hh < 2; ++hh) {
    const int h = w * 2 + hh;
    float* g = sc + base + h * 1024;
    float4 v0 = *(const float4*)&g[lane * 4];
    float4 v1 = *(const float4*)&g[256 + lane * 4];
    float4 v2 = *(const float4*)&g[512 + lane * 4];
    float4 v3 = *(const float4*)&g[768 + lane * 4];
    float mx = fmaxf(fmaxf(fmaxf(v0.x, v0.y), fmaxf(v0.z, v0.w)),
                     fmaxf(fmaxf(v1.x, v1.y), fmaxf(v1.z, v1.w)));
    mx = fmaxf(mx, fmaxf(fmaxf(fmaxf(v2.x, v2.y), fmaxf(v2.z, v2.w)),
                         fmaxf(fmaxf(v3.x, v3.y), fmaxf(v3.z, v3.w))));
#pragma unroll
    for (int off = 32; off > 0; off >>= 1)
      mx = fmaxf(mx, __shfl_xor(mx, off, 64));
    v0.x = __expf(v0.x - mx); v0.y = __expf(v0.y - mx);
    v0.z = __expf(v0.z - mx); v0.w = __expf(v0.w - mx);
    v1.x = __expf(v1.x - mx); v1.y = __expf(v1.y - mx);
    v1.z = __expf(v1.z - mx); v1.w = __expf(v1.w - mx);
    v2.x = __expf(v2.x - mx); v2.y = __expf(v2.y - mx);
    v2.z = __expf(v2.z - mx); v2.w = __expf(v2.w - mx);
    v3.x = __expf(v3.x - mx); v3.y = __expf(v3.y - mx);
    v3.z = __expf(v3.z - mx); v3.w = __expf(v3.w - mx);
    float sm = v0.x + v0.y + v0.z + v0.w + v1.x + v1.y + v1.z + v1.w +
               v2.x + v2.y + v2.z + v2.w + v3.x + v3.y + v3.z + v3.w;
#pragma unroll
    for (int off = 32; off > 0; off >>= 1) sm += __shfl_xor(sm, off, 64);
    const float inv = 1.f / sm;
    v0.x *= inv; v0.y *= inv; v0.z *= inv; v0.w *= inv;
    v1.x *= inv; v1.y *= inv; v1.z *= inv; v1.w *= inv;
    v2.x *= inv; v2.y *= inv; v2.z *= inv; v2.w *= inv;
    v3.x *= inv; v3.y *= inv; v3.z *= inv; v3.w *= inv;
    *(float4*)&g[lane * 4] = v0;
    *(float4*)&g[256 + lane * 4] = v1;
    *(float4*)&g[512 + lane * 4] = v2;
    *(float4*)&g[768 + lane * 4] = v3;
    float* r = rows + h * 1024;
    *(float4*)&r[lane * 4] = v0;
    *(float4*)&r[256 + lane * 4] = v1;
    *(float4*)&r[512 + lane * 4] = v2;
    *(float4*)&r[768 + lane * 4] = v3;
  }
  __syncthreads();
#pragma unroll
  for (int p = 0; p < 4; ++p) {
    const int s = p * 256 + t;
    float sum = 0.f;
#pragma unroll
    for (int h = 0; h < 8; ++h) sum += rows[h * 1024 + s];
    out[131072u + (m * Bb + b) * Ss + s] = sum * 0.125f;
  }
}

// ---------------------------------------------------------------------------
// K4a (fp16 MFMA, dbuf): w(m,b,h,k) = sum_s aw(m,b,h,s)*value(s,b,k)
__global__ __launch_bounds__(256) void k4a_av(const float* __restrict__ value,
                                              const float* __restrict__ aw,
                                              float* __restrict__ wout) {
  __shared__ unsigned Ap[2][64 * 20];  // aw packed   [mh][sp]
  __shared__ unsigned Vp[2][32 * 20];  // value^T pk  [k][sp]
  const int b = blockIdx.x, ko = blockIdx.y, t = threadIdx.x;
  const int w = t >> 6, lane = t & 63, quad = lane >> 4, l15 = lane & 15;
  const int amh = t >> 2, asg = t & 3;
  const float* ag =
      aw + ((size_t)((amh >> 3) * Bb + b) * Hh + (amh & 7)) * Ss + asg * 8;
  const int vk = (t & 15) * 2, vsp = t >> 4;
  const float* vg = value + (size_t)(2 * vsp) * (Bb * Kk) + b * Kk +
                    ko * 32 + vk;
  const size_t srow = (size_t)(Bb * Kk);
  float4 pa[2][2];
  float2 pv[2][2];
  f32x4 acc[2];
  acc[0] = (f32x4){0.f, 0.f, 0.f, 0.f};
  acc[1] = (f32x4){0.f, 0.f, 0.f, 0.f};

#define K4_LOAD(c, s)                                         \
  {                                                           \
    pa[s][0] = *(const float4*)(ag + (c) * 32);               \
    pa[s][1] = *(const float4*)(ag + (c) * 32 + 4);           \
    const float* vb = vg + (size_t)(c) * 32 * srow;           \
    pv[s][0] = *(const float2*)vb;                            \
    pv[s][1] = *(const float2*)(vb + srow);                   \
  }
#define K4_STORE(buf, s)                                                   \
  {                                                                        \
    uint4 v;                                                               \
    v.x = pk2(pa[s][0].x, pa[s][0].y); v.y = pk2(pa[s][0].z, pa[s][0].w);  \
    v.z = pk2(pa[s][1].x, pa[s][1].y); v.w = pk2(pa[s][1].z, pa[s][1].w);  \
    *(uint4*)&Ap[buf][amh * 20 + asg * 4] = v;                             \
    Vp[buf][vk * 20 + vsp] = pk2(pv[s][0].x, pv[s][1].x);                  \
    Vp[buf][(vk + 1) * 20 + vsp] = pk2(pv[s][0].y, pv[s][1].y);            \
  }

  K4_LOAD(0, 0); K4_STORE(0, 0);
  K4_LOAD(1, 1);
#pragma unroll
  for (int c = 0; c < 32; ++c) {
    __syncthreads();
    if (c + 2 < 32) K4_LOAD(c + 2, c & 1);
    const f16x8 af = *(const f16x8*)&Ap[c & 1][(w * 16 + l15) * 20 + quad * 4];
#pragma unroll
    for (int nt = 0; nt < 2; ++nt) {
      const f16x8 bf =
          *(const f16x8*)&Vp[c & 1][(nt * 16 + l15) * 20 + quad * 4];
      acc[nt] =
          __builtin_amdgcn_mfma_f32_16x16x32_f16(af, bf, acc[nt], 0, 0, 0);
    }
    if (c + 1 < 32) K4_STORE((c + 1) & 1, (c + 1) & 1);
  }
#pragma unroll
  for (int nt = 0; nt < 2; ++nt) {
    const int k = ko * 32 + nt * 16 + l15;
#pragma unroll
    for (int r = 0; r < 4; ++r) {
      const int mh = w * 16 + quad * 4 + r;
      wout[((size_t)((mh >> 3) * Bb + b) * Hh + (mh & 7)) * Kk + k] =
          acc[nt][r];
    }
  }
#undef K4_LOAD
#undef K4_STORE
}

// ---------------------------------------------------------------------------
// K5: ctx = w @ Wv_h + bv ; attn_out = ctx @ Wo + bo ; fc_in = relu(concat)
__global__ __launch_bounds__(256) void k5_ctx(
    const float* __restrict__ wv, const float* __restrict__ bv,
    const float* __restrict__ wo, const float* __restrict__ bo,
    const float* __restrict__ s0in, const float* __restrict__ w,
    float* __restrict__ attn_out, float* __restrict__ fc) {
  __shared__ float wsh[2048];
  __shared__ float ctxs[256];
  const int m = blockIdx.x, b = blockIdx.y, t = threadIdx.x;
  const int base = (m * Bb + b) * (Hh * Kk);
#pragma unroll
  for (int p = 0; p < 8; ++p) wsh[p * 256 + t] = w[base + p * 256 + t];
  __syncthreads();
  const int h = t >> 5;
  float acc = bv[m * Kk + t];
  const float* wvc = wv + m * Kk * Kk + t;
  for (int k4 = 0; k4 < 64; ++k4) {
    const float4 a4 = *(const float4*)&wsh[h * 256 + k4 * 4];
    acc += a4.x * wvc[(k4 * 4 + 0) * Kk] + a4.y * wvc[(k4 * 4 + 1) * Kk] +
           a4.z * wvc[(k4 * 4 + 2) * Kk] + a4.w * wvc[(k4 * 4 + 3) * Kk];
  }
  ctxs[t] = acc;
  __syncthreads();
  float acc2 = bo[m * Kk + t];
  const float* woc = wo + m * Kk * Kk + t;
  for (int k4 = 0; k4 < 64; ++k4) {
    const float4 c4 = *(const float4*)&ctxs[k4 * 4];
    acc2 += c4.x * woc[(k4 * 4 + 0) * Kk] + c4.y * woc[(k4 * 4 + 1) * Kk] +
            c4.z * woc[(k4 * 4 + 2) * Kk] + c4.w * woc[(k4 * 4 + 3) * Kk];
  }
  const int ob = (m * Bb + b) * Kk + t;
  attn_out[ob] = acc2;
  fc[(m * Bb + b) * 512 + t] = fmaxf(acc2, 0.f);
  fc[(m * Bb + b) * 512 + 256 + t] = fmaxf(s0in[ob], 0.f);
}

// ---------------------------------------------------------------------------
// K6 (fp16 MFMA, dbuf): h1[head] = relu(fc_in @ W1[head] + b1[head])
// W tile in LDS as [kp][f] (stride 68): uint4 stores (min-conflict),
// fragment reads 4x b32 at 2-way-free banking.
__global__ __launch_bounds__(256) void k6_mlp1(
    const float* __restrict__ fc, const float* __restrict__ w1q,
    const float* __restrict__ w1k, const float* __restrict__ w1v,
    const float* __restrict__ w1s, const float* __restrict__ w1g,
    const float* __restrict__ b1q, const float* __restrict__ b1k,
    const float* __restrict__ b1v, const float* __restrict__ b1s,
    const float* __restrict__ b1g, float* __restrict__ h1) {
  __shared__ unsigned As[2][64 * 20];  // fc packed  [b][kp]
  __shared__ unsigned Ws[2][16 * 68];  // W1^T packed [kp][f]
  const int ft = blockIdx.x, m = blockIdx.y, head = blockIdx.z,
            t = threadIdx.x;
  const float* w1;
  const float* b1;
  if (head == 0)      { w1 = w1q; b1 = b1q; }
  else if (head == 1) { w1 = w1k; b1 = b1k; }
  else if (head == 2) { w1 = w1v; b1 = b1v; }
  else if (head == 3) { w1 = w1s; b1 = b1s; }
  else {
    w1 = w1g + (size_t)(head - 4) * (Mm * 512 * Ff);
    b1 = b1g + (head - 4) * (Mm * Ff);
  }
  w1 += (size_t)m * 512 * Ff;
  b1 += m * Ff;
  const int w = t >> 6, lane = t & 63, quad = lane >> 4, l15 = lane & 15;
  const int abb = t >> 2, akg = t & 3;
  const float* ag = fc + (m * Bb + abb) * 512 + akg * 8;
  const int wf0 = (t & 15) * 4, wkp = t >> 4;
  const float* wg = w1 + (size_t)(2 * wkp) * Ff + ft * 64 + wf0;
  float4 pa[2][2], pw[2][2];
  f32x4 acc[4];
#pragma unroll
  for (int i = 0; i < 4; ++i) acc[i] = (f32x4){0.f, 0.f, 0.f, 0.f};

#define K6_LOAD(c, s)                                            \
  {                                                              \
    pa[s][0] = *(const float4*)(ag + (c) * 32);                  \
    pa[s][1] = *(const float4*)(ag + (c) * 32 + 4);              \
    const float* wb = wg + (size_t)(c) * 32 * Ff;                \
    pw[s][0] = *(const float4*)wb;                               \
    pw[s][1] = *(const float4*)(wb + Ff);                        \
  }
#define K6_STORE(buf, s)                                                   \
  {                                                                        \
    uint4 v;                                                               \
    v.x = pk2(pa[s][0].x, pa[s][0].y); v.y = pk2(pa[s][0].z, pa[s][0].w);  \
    v.z = pk2(pa[s][1].x, pa[s][1].y); v.w = pk2(pa[s][1].z, pa[s][1].w);  \
    *(uint4*)&As[buf][abb * 20 + akg * 4] = v;                             \
    uint4 wv_;                                                             \
    wv_.x = pk2(pw[s][0].x, pw[s][1].x);                                   \
    wv_.y = pk2(pw[s][0].y, pw[s][1].y);                                   \
    wv_.z = pk2(pw[s][0].z, pw[s][1].z);                                   \
    wv_.w = pk2(pw[s][0].w, pw[s][1].w);                                   \
    *(uint4*)&Ws[buf][wkp * 68 + wf0] = wv_;                               \
  }

  K6_LOAD(0, 0); K6_STORE(0, 0);
  K6_LOAD(1, 1);
#pragma unroll
  for (int c = 0; c < 16; ++c) {
    __syncthreads();
    if (c + 2 < 16) K6_LOAD(c + 2, c & 1);
    union { f16x8 v; unsigned u[4]; } bfu;
#pragma unroll
    for (int j = 0; j < 4; ++j)
      bfu.u[j] = Ws[c & 1][(quad * 4 + j) * 68 + w * 16 + l15];
    const f16x8 bf = bfu.v;
#pragma unroll
    for (int mt = 0; mt < 4; ++mt) {
      const f16x8 af =
          *(const f16x8*)&As[c & 1][(mt * 16 + l15) * 20 + quad * 4];
      acc[mt] =
          __builtin_amdgcn_mfma_f32_16x16x32_f16(af, bf, acc[mt], 0, 0, 0);
    }
    if (c + 1 < 16) K6_STORE((c + 1) & 1, (c + 1) & 1);
  }
  const int f = ft * 64 + w * 16 + l15;
  const float bias = b1[f];
  float* hb = h1 + (size_t)((head * Mm + m) * Bb) * Ff + f;
#pragma unroll
  for (int mt = 0; mt < 4; ++mt) {
#pragma unroll
    for (int r = 0; r < 4; ++r) {
      const int bb = mt * 16 + quad * 4 + r;
      hb[(size_t)bb * Ff] = fmaxf(acc[mt][r] + bias, 0.f);
    }
  }
#undef K6_LOAD
#undef K6_STORE
}

// ---------------------------------------------------------------------------
// K6b: gates(g,m,b) = sigmoid(h1[4+g,m,b,:] . g_w2[g,m,:] + g_b2[g,m])
__global__ __launch_bounds__(64) void k6b_gates(
    const float* __restrict__ h1, const float* __restrict__ gw2,
    const float* __restrict__ gb2, float* __restrict__ gates) {
  const int gm = blockIdx.x, b = blockIdx.y, t = threadIdx.x;
  const int g = gm >> 3, m = gm & 7;
  const float* hrow = h1 + (size_t)(((4 + g) * Mm + m) * Bb + b) * Ff;
  const float* wrow = gw2 + (g * Mm + m) * Ff;
  float s = 0.f;
#pragma unroll
  for (int i = 0; i < 16; ++i) s += hrow[t + i * 64] * wrow[t + i * 64];
  for (int off = 32; off > 0; off >>= 1) s += __shfl_down(s, off, 64);
  if (t == 0)
    gates[(g * Mm + m) * Bb + b] =
        1.f / (1.f + __expf(-(s + gb2[g * Mm + m])));
}

// ---------------------------------------------------------------------------
// K7a (fp16 MFMA, dbuf): partial head outputs, k-split 4 over f.
// grid (16, 8, 4): (ot + 4*fq, m, head). Block = 64 b x 64 o over f-quarter.
__global__ __launch_bounds__(256) void k7a_mlp2(
    const float* __restrict__ h1, const float* __restrict__ w2q,
    const float* __restrict__ w2k, const float* __restrict__ w2v,
    const float* __restrict__ w2s, float* __restrict__ hpart) {
  __shared__ unsigned As[2][64 * 20];  // h1 packed  [b][fp]
  __shared__ unsigned Ws[2][16 * 68];  // w2^T packed [fp][o]
  const int ot = blockIdx.x & 3, fq = blockIdx.x >> 2;
  const int m = blockIdx.y, head = blockIdx.z, t = threadIdx.x;
  const float* w2 =
      (head == 0) ? w2q : (head == 1) ? w2k : (head == 2) ? w2v : w2s;
  w2 += (size_t)m * Ff * Kk;
  const int w = t >> 6, lane = t & 63, quad = lane >> 4, l15 = lane & 15;
  const int abb = t >> 2, akg = t & 3;
  const float* ag =
      h1 + (size_t)((head * Mm + m) * Bb + abb) * Ff + fq * 256 + akg * 8;
  const int wf0 = (t & 15) * 4, wkp = t >> 4;
  const float* wg = w2 + (size_t)(fq * 256 + 2 * wkp) * Kk + ot * 64 + wf0;
  float4 pa[2][2], pw[2][2];
  f32x4 acc[4];
#pragma unroll
  for (int i = 0; i < 4; ++i) acc[i] = (f32x4){0.f, 0.f, 0.f, 0.f};

#define K7_LOAD(c, s)                                            \
  {                                                              \
    pa[s][0] = *(const float4*)(ag + (c) * 32);                  \
    pa[s][1] = *(const float4*)(ag + (c) * 32 + 4);              \
    const float* wb = wg + (size_t)(c) * 32 * Kk;                \
    pw[s][0] = *(const float4*)wb;                               \
    pw[s][1] = *(const float4*)(wb + Kk);                        \
  }
#define K7_STORE(buf, s)                                                   \
  {                                                                        \
    uint4 v;                                                               \
    v.x = pk2(pa[s][0].x, pa[s][0].y); v.y = pk2(pa[s][0].z, pa[s][0].w);  \
    v.z = pk2(pa[s][1].x, pa[s][1].y); v.w = pk2(pa[s][1].z, pa[s][1].w);  \
    *(uint4*)&As[buf][abb * 20 + akg * 4] = v;                             \
    uint4 wv_;                                                             \
    wv_.x = pk2(pw[s][0].x, pw[s][1].x);                                   \
    wv_.y = pk2(pw[s][0].y, pw[s][1].y);                                   \
    wv_.z = pk2(pw[s][0].z, pw[s][1].z);                                   \
    wv_.w = pk2(pw[s][0].w, pw[s][1].w);                                   \
    *(uint4*)&Ws[buf][wkp * 68 + wf0] = wv_;                               \
  }

  K7_LOAD(0, 0); K7_STORE(0, 0);
  K7_LOAD(1, 1);
#pragma unroll
  for (int c = 0; c < 8; ++c) {
    __syncthreads();
    if (c + 2 < 8) K7_LOAD(c + 2, c & 1);
    union { f16x8 v; unsigned u[4]; } bfu;
#pragma unroll
    for (int j = 0; j < 4; ++j)
      bfu.u[j] = Ws[c & 1][(quad * 4 + j) * 68 + w * 16 + l15];
    const f16x8 bf = bfu.v;
#pragma unroll
    for (int mt = 0; mt < 4; ++mt) {
      const f16x8 af =
          *(const f16x8*)&As[c & 1][(mt * 16 + l15) * 20 + quad * 4];
      acc[mt] =
          __builtin_amdgcn_mfma_f32_16x16x32_f16(af, bf, acc[mt], 0, 0, 0);
    }
    if (c + 1 < 8) K7_STORE((c + 1) & 1, (c + 1) & 1);
  }
  const int o = ot * 64 + w * 16 + l15;
  float* hp =
      hpart + fq * 524288u + (size_t)((head * Mm + m) * Bb) * Kk + o;
#pragma unroll
  for (int mt = 0; mt < 4; ++mt) {
#pragma unroll
    for (int r = 0; r < 4; ++r) {
      const int bb = mt * 16 + quad * 4 + r;
      hp[(size_t)bb * Kk] = acc[mt][r];
    }
  }
#undef K7_LOAD
#undef K7_STORE
}

// ---------------------------------------------------------------------------
// K7b: out = gate*tanh(relu(p0+p1+p2+p3+b2)) + (1-gate)*x0
__global__ __launch_bounds__(256) void k7b_final(
    const float* __restrict__ hpart, const float* __restrict__ gates,
    const float* __restrict__ b2q, const float* __restrict__ b2k,
    const float* __restrict__ b2v, const float* __restrict__ b2s,
    const float* __restrict__ q0, const float* __restrict__ k0,
    const float* __restrict__ v0, const float* __restrict__ s0,
    float* __restrict__ out) {
  const int idx = blockIdx.x * 256 + threadIdx.x;
  const int o = idx & 255;
  const int b = (idx >> 8) & 63;
  const int m = (idx >> 14) & 7;
  const int head = idx >> 17;
  const float* b2 = (head == 0) ? b2q : (head == 1) ? b2k
                    : (head == 2) ? b2v : b2s;
  const float* x0 = (head == 0) ? q0 : (head == 1) ? k0
                    : (head == 2) ? v0 : s0;
  const unsigned ooff = (head == 0) ? 786432u
                        : (head == 1) ? 917504u
                        : (head == 2) ? 1048576u : 655360u;
  float v = hpart[idx] + hpart[524288u + idx] + hpart[1048576u + idx] +
            hpart[1572864u + idx] + b2[m * Kk + o];
  v = tanhf(fmaxf(v, 0.f));
  const float g = gates[(head * Mm + m) * Bb + b];
  const float x = x0[(m * Bb + b) * Kk + o];
  out[ooff + (m * Bb + b) * Kk + o] = g * v + (1.f - g) * x;
}

// ---------------------------------------------------------------------------
extern "C" void kernel_launch(void* const* d_in, const int* in_sizes, int n_in,
                              void* d_out, int out_size, void* d_ws,
                              size_t ws_size, hipStream_t stream) {
  (void)in_sizes; (void)n_in; (void)out_size; (void)ws_size;
  const float* s0  = (const float*)d_in[0];
  const float* q0  = (const float*)d_in[1];
  const float* k0  = (const float*)d_in[2];
  const float* v0  = (const float*)d_in[3];
  const float* key = (const float*)d_in[4];
  const float* val = (const float*)d_in[5];
  const float* wq  = (const float*)d_in[6];
  const float* wk  = (const float*)d_in[7];
  const float* wv  = (const float*)d_in[8];
  const float* bqa = (const float*)d_in[9];
  const float* bka = (const float*)d_in[10];
  const float* bva = (const float*)d_in[11];
  const float* wo  = (const float*)d_in[12];
  const float* bo  = (const float*)d_in[13];
  const float* qw1 = (const float*)d_in[14];
  const float* qb1 = (const float*)d_in[15];
  const float* qw2 = (const float*)d_in[16];
  const float* qb2 = (const float*)d_in[17];
  const float* kw1 = (const float*)d_in[18];
  const float* kb1 = (const float*)d_in[19];
  const float* kw2 = (const float*)d_in[20];
  const float* kb2 = (const float*)d_in[21];
  const float* vw1 = (const float*)d_in[22];
  const float* vb1 = (const float*)d_in[23];
  const float* vw2 = (const float*)d_in[24];
  const float* vb2 = (const float*)d_in[25];
  const float* sw1 = (const float*)d_in[26];
  const float* sb1 = (const float*)d_in[27];
  const float* sw2 = (const float*)d_in[28];
  const float* sb2 = (const float*)d_in[29];
  const float* gw1 = (const float*)d_in[30];
  const float* gb1 = (const float*)d_in[31];
  const float* gw2 = (const float*)d_in[32];
  const float* gb2 = (const float*)d_in[33];
  float* ws  = (float*)d_ws;
  float* out = (float*)d_out;

  k1_qproj<<<dim3(8, 8), 256, 0, stream>>>(q0, wq, bqa, ws + WS_Q);
  k2_uproj<<<dim3(8, 8), 256, 0, stream>>>(wk, bka, ws + WS_Q, ws + WS_U,
                                           ws + WS_QDB);
  k3_scores<<<dim3(64, 16), 256, 0, stream>>>(key, ws + WS_U, ws + WS_QDB,
                                              ws + WS_SC);
  k3b_softmax<<<dim3(8, 64), 256, 0, stream>>>(ws + WS_SC, out);
  k4a_av<<<dim3(64, 8), 256, 0, stream>>>(val, ws + WS_SC, ws + WS_W);
  k5_ctx<<<dim3(8, 64), 256, 0, stream>>>(wv, bva, wo, bo, s0, ws + WS_W, out,
                                          ws + WS_FC);
  k6_mlp1<<<dim3(16, 8, 8), 256, 0, stream>>>(ws + WS_FC, qw1, kw1, vw1, sw1,
                                              gw1, qb1, kb1, vb1, sb1, gb1,
                                              ws + WS_H1);
  k6b_gates<<<dim3(32, 64), 64, 0, stream>>>(ws + WS_H1, gw2, gb2,
                                             ws + WS_GATES);
  k7a_mlp2<<<dim3(16, 8, 4), 256, 0, stream>>>(ws + WS_H1, qw2, kw2, vw2, sw2,
                                               ws + WS_HPART);
  k7b_final<<<dim3(2048), 256, 0, stream>>>(ws + WS_HPART, ws + WS_GATES, qb2,
                                            kb2, vb2, sb2, q0, k0, v0, s0,
                                            out);
}